// Round 8
// baseline (632.033 us; speedup 1.0000x reference)
//
#include <hip/hip_runtime.h>
#include <math.h>

// ValueNetwork forward. conv2 via split-bf16 MFMA (3-pass hi/lo), quarter-K LDS.
// ws layout (floats):
//  f    [64][32][128]        @ 0        (262144)
//  R    [64][3][64][128]     @ 262144   (1572864)
//  C    [64][3][64][128]     @ 1835008  (1572864)
//  D    [64][64][128][5]     @ 3407872  (2621440)
//  afa  [64][32][128]        @ 6029312  (262144)
//  smi  [64][128][64]        @ 6291456  (524288)
//  wts  [64][128]            @ 6815744  (8192)
//  rh   [64][64][128]        @ 6823936  (524288)
//  hnm  [64][64]             @ 7348224  (4096)
//  Apack[2][9][4][64][8] u16 @ 7352320  (18432 f32-equiv)
//  so   [64][128][32]        @ 7376896  (262144)
//  gst  [64][32]             @ 7639040  (2048)
//  se   [64][128]            @ 7641088  (8192)

typedef short bf16x4 __attribute__((ext_vector_type(4)));
typedef short bf16x8 __attribute__((ext_vector_type(8)));
typedef float f32x16 __attribute__((ext_vector_type(16)));

__device__ inline unsigned int bf16_rne(float x) {
  unsigned int u = __float_as_uint(x);
  return (u + 0x7fffu + ((u >> 16) & 1u)) >> 16;
}

#define MF(A, B, Cc) __builtin_amdgcn_mfma_f32_32x32x16_bf16((A), (B), (Cc), 0, 0, 0)

// k0: pack w_c2 [o2 32][cin 64][rx 9] fp32 -> Apack[p2][rx9][chunk4][lane64][8] bf16
__global__ __launch_bounds__(256) void k0_pack(const float* __restrict__ w_c2,
                                               unsigned short* __restrict__ Apack) {
  for (int idx = threadIdx.x; idx < 36864; idx += 256) {
    int p = idx / 18432, rem = idx % 18432;
    int rx = rem >> 11, r2 = rem & 2047;
    int chunk = r2 >> 9, r3 = r2 & 511;
    int lane = r3 >> 3, i8 = r3 & 7;
    int o2 = lane & 31, k8 = lane >> 5;
    int cin = chunk * 16 + k8 * 8 + i8;
    float v = w_c2[(o2 * 64 + cin) * 9 + rx];
    unsigned int hi = bf16_rne(v);
    float hif = __uint_as_float(hi << 16);
    unsigned int lo = bf16_rne(v - hif);
    Apack[idx] = (unsigned short)(p ? lo : hi);
  }
}

// front MLP: agents(7) -> 64 relu -> 32 relu, f[b][c][n]
__global__ __launch_bounds__(128) void k1_front(
    const float* __restrict__ state, const float* __restrict__ w_in1,
    const float* __restrict__ b_in1, const float* __restrict__ w_in2,
    const float* __restrict__ b_in2, float* __restrict__ f) {
  int b = blockIdx.x, nq = blockIdx.y, t = threadIdx.x;
  int row = t >> 2, lane = t & 3;
  int n = nq * 32 + row;
  __shared__ float hs[32][66];
  const float* st = state + (b * 128 + n) * 13 + 6;
  float a[7];
#pragma unroll
  for (int k = 0; k < 7; k++) a[k] = st[k];
  for (int oi = 0; oi < 16; oi++) {
    int o = lane * 16 + oi;
    float acc = b_in1[o];
#pragma unroll
    for (int k = 0; k < 7; k++) acc += w_in1[o * 7 + k] * a[k];
    hs[row][o] = fmaxf(acc, 0.f);
  }
  __syncthreads();
  for (int ci = 0; ci < 8; ci++) {
    int c = lane * 8 + ci;
    float acc = b_in2[c];
#pragma unroll 8
    for (int k = 0; k < 64; k++) acc += w_in2[c * 64 + k] * hs[row][k];
    f[(b * 32 + c) * 128 + n] = fmaxf(acc, 0.f);
  }
}

// conv1 low-rank precompute. grid (og=16, b=64), 128 threads = i; 4 o per block.
__global__ __launch_bounds__(128) void k2_pre(
    const float* __restrict__ f, const float* __restrict__ w_c1,
    float* __restrict__ R, float* __restrict__ C, float* __restrict__ D) {
  int og = blockIdx.x, b = blockIdx.y, t = threadIdx.x;
  int o0 = og * 4;
  __shared__ float fL[4096];
  __shared__ float w1s[1152];
  __shared__ float wrow[1152];
  __shared__ float wcol[1152];
  for (int idx = t; idx < 4096; idx += 128) fL[idx] = f[b * 4096 + idx];
  for (int idx = t; idx < 1152; idx += 128) w1s[idx] = w_c1[o0 * 288 + idx];
  __syncthreads();
  if (t < 128) {
    int ol = t >> 5, c = t & 31;
    int base = ol * 288 + c * 9;
#pragma unroll
    for (int di = 0; di < 3; di++) {
      float w0 = w1s[base + di * 3 + 0], w1 = w1s[base + di * 3 + 1],
            w2 = w1s[base + di * 3 + 2];
      wrow[ol * 288 + (c * 3 + di) * 3 + 0] = w1 + w2;
      wrow[ol * 288 + (c * 3 + di) * 3 + 1] = w0 + w1 + w2;
      wrow[ol * 288 + (c * 3 + di) * 3 + 2] = w0 + w1;
    }
#pragma unroll
    for (int dj = 0; dj < 3; dj++) {
      float w0 = w1s[base + 0 * 3 + dj], w1 = w1s[base + 1 * 3 + dj],
            w2 = w1s[base + 2 * 3 + dj];
      wcol[ol * 288 + (c * 3 + dj) * 3 + 0] = w1 + w2;
      wcol[ol * 288 + (c * 3 + dj) * 3 + 1] = w0 + w1 + w2;
      wcol[ol * 288 + (c * 3 + dj) * 3 + 2] = w0 + w1;
    }
  }
  __syncthreads();
  int i = t;
  for (int ol = 0; ol < 4; ol++) {
    int o = o0 + ol;
    float r0 = 0, r1 = 0, r2 = 0, c0 = 0, c1 = 0, c2 = 0;
    float d0 = 0, d1 = 0, d2 = 0, d3 = 0, d4 = 0;
    for (int c = 0; c < 32; c++) {
      float fm = (i >= 1) ? fL[c * 128 + i - 1] : 0.f;
      float f0 = fL[c * 128 + i];
      float fp = (i < 127) ? fL[c * 128 + i + 1] : 0.f;
      const float* wr = &wrow[ol * 288 + c * 9];
      r0 += fm * wr[0] + f0 * wr[3] + fp * wr[6];
      r1 += fm * wr[1] + f0 * wr[4] + fp * wr[7];
      r2 += fm * wr[2] + f0 * wr[5] + fp * wr[8];
      const float* wc = &wcol[ol * 288 + c * 9];
      c0 += fm * wc[0] + f0 * wc[3] + fp * wc[6];
      c1 += fm * wc[1] + f0 * wc[4] + fp * wc[7];
      c2 += fm * wc[2] + f0 * wc[5] + fp * wc[8];
      const float* wp = &w1s[ol * 288 + c * 9];
      d0 += fm * wp[2];
      d1 += fm * wp[1] + f0 * wp[5];
      d2 += fm * wp[0] + f0 * wp[4] + fp * wp[8];
      d3 += f0 * wp[3] + fp * wp[7];
      d4 += fp * wp[6];
    }
    R[((b * 3 + 0) * 64 + o) * 128 + i] = r0;
    R[((b * 3 + 1) * 64 + o) * 128 + i] = r1;
    R[((b * 3 + 2) * 64 + o) * 128 + i] = r2;
    C[((b * 3 + 0) * 64 + o) * 128 + i] = c0;
    C[((b * 3 + 1) * 64 + o) * 128 + i] = c1;
    C[((b * 3 + 2) * 64 + o) * 128 + i] = c2;
    float* dp = &D[((b * 64 + o) * 128 + i) * 5];
    dp[0] = d0; dp[1] = d1; dp[2] = d2; dp[3] = d3; dp[4] = d4;
  }
}

// k3: conv2 via MFMA + softmax + afa. grid (iblk=64, b=64), 256 thr.
// Dynamic LDS 40960 B: G[prec2][ipl4][j128][stride 20 u16] (cc 0..15 valid).
// Quarter K-chunks; x-outer MFMA loop with B-row cache, A loaded on demand.
// EPILOGUE LOOPS MUST BE FULLY UNROLLED: partial unroll (#pragma unroll 8)
// made vals[]/fj[] dynamically indexed -> scratch arrays -> 135 MB of HBM
// scratch traffic (rounds 5-7 post-mortem, WRITE_SIZE counter).
__global__ __launch_bounds__(256, 3) void k3_conv2(
    const float* __restrict__ f, const float* __restrict__ R,
    const float* __restrict__ C, const float* __restrict__ D,
    const float* __restrict__ b_c1, const unsigned short* __restrict__ Apack,
    const float* __restrict__ b_c2, float* __restrict__ afa) {
  extern __shared__ unsigned short G[];  // 20480 u16 = 40960 B
  int iblk = blockIdx.x, b = blockIdx.y, t = threadIdx.x;
  int i0 = iblk * 2;
  int lane = t & 63, jt = t >> 6;
  int nn = lane & 31;
  int kh8 = (lane >> 5) * 8;
  const bf16x8* A8 = (const bf16x8*)Apack;
  bf16x8 zero8 = {0, 0, 0, 0, 0, 0, 0, 0};
  f32x16 acc0 = {0, 0, 0, 0, 0, 0, 0, 0, 0, 0, 0, 0, 0, 0, 0, 0};
  f32x16 acc1 = {0, 0, 0, 0, 0, 0, 0, 0, 0, 0, 0, 0, 0, 0, 0, 0};

  // rebuild mapping: lane jlane = consecutive j (bank spread + coalescing)
  int jlane = t & 31;
  int iplr = (t >> 5) & 3;
  int ch = t >> 7;
  int ipr = i0 - 1 + iplr;
  bool rowok = (ipr >= 0 && ipr <= 127);
  int ipc = ipr < 0 ? 0 : (ipr > 127 ? 127 : ipr);
  int ic = (ipc == 0) ? 0 : ((ipc == 127) ? 2 : 1);

  for (int qt = 0; qt < 4; qt++) {
    if (qt) __syncthreads();
    // ---- rebuild G for cin = qt*16 .. +15 ----
#pragma unroll
    for (int cp = 0; cp < 4; cp++) {
      int cc0 = (ch * 4 + cp) * 2;
      int cin0 = qt * 16 + cc0;
      float bias0 = b_c1[cin0], bias1 = b_c1[cin0 + 1];
      float base0 = R[((b * 3 + 1) * 64 + cin0) * 128 + ipc] + bias0;
      float base1 = R[((b * 3 + 1) * 64 + cin0 + 1) * 128 + ipc] + bias1;
      float eb00 = 0, eb01 = 0, eb20 = 0, eb21 = 0;
      if (jlane == 0) {
        eb00 = R[((b * 3 + 0) * 64 + cin0) * 128 + ipc] + bias0;
        eb01 = R[((b * 3 + 0) * 64 + cin0 + 1) * 128 + ipc] + bias1;
      }
      if (jlane == 31) {
        eb20 = R[((b * 3 + 2) * 64 + cin0) * 128 + ipc] + bias0;
        eb21 = R[((b * 3 + 2) * 64 + cin0 + 1) * 128 + ipc] + bias1;
      }
      const float* C0 = &C[((b * 3 + ic) * 64 + cin0) * 128];
      const float* C1 = C0 + 128;
      const float* D0 = &D[((b * 64 + cin0) * 128 + ipc) * 5];
      const float* D1 = D0 + 640;
#pragma unroll
      for (int jr = 0; jr < 4; jr++) {
        int j = jlane + jr * 32;
        float c0v = C0[j], c1v = C1[j];
        float v0 = base0 - c0v, v1 = base1 - c1v;
        if (j == 0) { v0 = eb00 - c0v; v1 = eb01 - c1v; }
        if (j == 127) { v0 = eb20 - c0v; v1 = eb21 - c1v; }
        int rel = j - ipr + 2;
        if (rel >= 0 && rel < 5) { v0 += D0[rel]; v1 += D1[rel]; }
        v0 = rowok ? fmaxf(v0, 0.f) : 0.f;
        v1 = rowok ? fmaxf(v1, 0.f) : 0.f;
        unsigned int h0 = bf16_rne(v0), h1 = bf16_rne(v1);
        float l0f = v0 - __uint_as_float(h0 << 16);
        float l1f = v1 - __uint_as_float(h1 << 16);
        unsigned int l0 = bf16_rne(l0f), l1 = bf16_rne(l1f);
        unsigned int off = (unsigned)((iplr * 128 + j) * 20 + cc0);
        *(unsigned int*)&G[off] = h0 | (h1 << 16);
        *(unsigned int*)&G[off + 10240] = l0 | (l1 << 16);
      }
    }
    __syncthreads();
    // ---- MFMA: x outer (B-row cache), r inner (A on demand) ----
#pragma unroll
    for (int x = 0; x < 3; x++) {
      int imgj = jt * 32 + nn + x - 1;
      int ij = imgj < 0 ? 0 : (imgj > 127 ? 127 : imgj);
      bool valid = (imgj >= 0 && imgj <= 127);
      bf16x8 bh[4], bl[4];
#pragma unroll
      for (int rr = 0; rr < 4; rr++) {
        int boff = (rr * 128 + ij) * 20 + kh8;
        bf16x4 h0 = *(const bf16x4*)&G[boff];
        bf16x4 h1 = *(const bf16x4*)&G[boff + 4];
        bf16x4 q0 = *(const bf16x4*)&G[boff + 10240];
        bf16x4 q1 = *(const bf16x4*)&G[boff + 10244];
        bf16x8 vh = __builtin_shufflevector(h0, h1, 0, 1, 2, 3, 4, 5, 6, 7);
        bf16x8 vl = __builtin_shufflevector(q0, q1, 0, 1, 2, 3, 4, 5, 6, 7);
        bh[rr] = valid ? vh : zero8;
        bl[rr] = valid ? vl : zero8;
      }
#pragma unroll
      for (int r = 0; r < 3; r++) {
        int rx = r * 3 + x;
        bf16x8 Ah = A8[(rx * 4 + qt) * 64 + lane];
        bf16x8 Al = A8[((9 + rx) * 4 + qt) * 64 + lane];
        acc0 = MF(Ah, bh[r], acc0);
        acc0 = MF(Ah, bl[r], acc0);
        acc0 = MF(Al, bh[r], acc0);
        acc1 = MF(Ah, bh[r + 1], acc1);
        acc1 = MF(Ah, bl[r + 1], acc1);
        acc1 = MF(Al, bh[r + 1], acc1);
      }
    }
  }
  __syncthreads();
  // ---- epilogue: logits -> LDS ----
  float* logits = (float*)G;  // 8192 f32 = 32 KB
#pragma unroll
  for (int reg = 0; reg < 16; reg++) {
    int o2 = (reg & 3) + 8 * (reg >> 2) + 4 * (lane >> 5);
    int j = jt * 32 + nn;
    logits[(0 * 32 + o2) * 128 + j] = acc0[reg];
    logits[(1 * 32 + o2) * 128 + j] = acc1[reg];
  }
  __syncthreads();
  // ---- softmax over j + weighted pair reduction (FULLY unrolled; see note) ----
  {
    int i2 = t >> 7, o2e = (t >> 2) & 31, qd = t & 3;
    const float* lrow = &logits[(i2 * 32 + o2e) * 128 + qd * 32];
    float bias2 = b_c2[o2e];
    float vals[32];
    float mx = -3.0e38f;
#pragma unroll
    for (int s = 0; s < 32; s++) {
      vals[s] = lrow[s] + bias2;
      mx = fmaxf(mx, vals[s]);
    }
    mx = fmaxf(mx, __shfl_xor(mx, 1));
    mx = fmaxf(mx, __shfl_xor(mx, 2));
    float sum = 0.f;
#pragma unroll
    for (int s = 0; s < 32; s++) {
      vals[s] = expf(vals[s] - mx);
      sum += vals[s];
    }
    sum += __shfl_xor(sum, 1);
    sum += __shfl_xor(sum, 2);
    float inv = 1.f / sum;
    int gi = i0 + i2;
    float fi = f[b * 4096 + o2e * 128 + gi];
    float fj[32];
    const float4* frow = (const float4*)&f[b * 4096 + o2e * 128 + qd * 32];
#pragma unroll
    for (int s4 = 0; s4 < 8; s4++) *(float4*)&fj[s4 * 4] = frow[s4];
    float part = 0.f;
#pragma unroll
    for (int s = 0; s < 32; s++) {
      int j = qd * 32 + s;
      float w = vals[s] * inv;
      part += w * (fi - fj[s]);
      if (j == gi) part += w * fi;
    }
    part += __shfl_xor(part, 1);
    part += __shfl_xor(part, 2);
    if (qd == 0) afa[(b * 32 + o2e) * 128 + gi] = part;
  }
}

// k4a: per (b,n): x -> h1 -> ia||self -> s1 -> so. grid 256 blocks, 256 thr.
__global__ __launch_bounds__(256) void k4a_sort(
    const float* __restrict__ state, const float* __restrict__ f,
    const float* __restrict__ afa, const float* __restrict__ w_ia1,
    const float* __restrict__ b_ia1, const float* __restrict__ w_ia2,
    const float* __restrict__ b_ia2, const float* __restrict__ w_s1,
    const float* __restrict__ b_s1, const float* __restrict__ w_s2,
    const float* __restrict__ b_s2, float* __restrict__ so_g) {
  int blk = blockIdx.x;
  int b = blk >> 2, nq = blk & 3;
  int t = threadIdx.x, row = t >> 3, lane = t & 7;
  int n = nq * 32 + row;
  __shared__ float bufA[32][40];
  __shared__ float bufB[32][72];
  {
    int c0 = lane * 4;
    float4 av = *(const float4*)&afa[b * 4096 + n * 32 + c0];
    bufA[row][c0 + 0] = f[b * 4096 + (c0 + 0) * 128 + n] + av.x;
    bufA[row][c0 + 1] = f[b * 4096 + (c0 + 1) * 128 + n] + av.y;
    bufA[row][c0 + 2] = f[b * 4096 + (c0 + 2) * 128 + n] + av.z;
    bufA[row][c0 + 3] = f[b * 4096 + (c0 + 3) * 128 + n] + av.w;
  }
  __syncthreads();
#pragma unroll
  for (int oi = 0; oi < 8; oi++) {
    int o = lane * 8 + oi;
    float a = b_ia1[o];
#pragma unroll 8
    for (int c = 0; c < 32; c++) a += w_ia1[o * 32 + c] * bufA[row][c];
    bufB[row][o] = fmaxf(a, 0.f);
  }
  __syncthreads();
  {
    float r0[4];
#pragma unroll
    for (int oi = 0; oi < 4; oi++) {
      int o = lane * 4 + oi;
      float a = b_ia2[o];
#pragma unroll 8
      for (int k = 0; k < 64; k++) a += w_ia2[o * 64 + k] * bufB[row][k];
      r0[oi] = a;
    }
    __syncthreads();
#pragma unroll
    for (int oi = 0; oi < 4; oi++) bufA[row][lane * 4 + oi] = r0[oi];
    if (lane == 0) {
#pragma unroll
      for (int k = 0; k < 6; k++)
        bufA[row][32 + k] = state[(b * 128 + n) * 13 + k];
    }
  }
  __syncthreads();
#pragma unroll
  for (int oi = 0; oi < 8; oi++) {
    int o = lane * 8 + oi;
    float a = b_s1[o];
#pragma unroll 2
    for (int k = 0; k < 38; k++) a += w_s1[o * 38 + k] * bufA[row][k];
    bufB[row][o] = fmaxf(a, 0.f);
  }
  __syncthreads();
#pragma unroll
  for (int oi = 0; oi < 4; oi++) {
    int o = lane * 4 + oi;
    float a = b_s2[o];
#pragma unroll 8
    for (int k = 0; k < 64; k++) a += w_s2[o * 64 + k] * bufB[row][k];
    so_g[(b * 128 + n) * 32 + o] = a;
  }
}

__global__ __launch_bounds__(128) void k4b_gstate(const float* __restrict__ so_g,
                                                  float* __restrict__ gst) {
  int b = blockIdx.x, t = threadIdx.x;
  int c = t & 31, part = t >> 5;
  __shared__ float red[4][32];
  float a = 0.f;
  for (int nn = 0; nn < 32; nn++) a += so_g[(b * 128 + part * 32 + nn) * 32 + c];
  red[part][c] = a;
  __syncthreads();
  if (t < 32) gst[b * 32 + t] =
      (red[0][t] + red[1][t] + red[2][t] + red[3][t]) * (1.f / 128.f);
}

__global__ __launch_bounds__(256) void k4c_attn(
    const float* __restrict__ so_g, const float* __restrict__ gst,
    const float* __restrict__ w_a1, const float* __restrict__ b_a1,
    const float* __restrict__ w_a2, const float* __restrict__ b_a2,
    const float* __restrict__ w_a3, const float* __restrict__ b_a3,
    float* __restrict__ smi, float* __restrict__ se_g) {
  int blk = blockIdx.x;
  int b = blk >> 2, nq = blk & 3;
  int t = threadIdx.x, row = t >> 3, lane = t & 7;
  int n = nq * 32 + row;
  __shared__ float bufA[32][72];
  __shared__ float bufB[32][72];
  {
    int c0 = lane * 4;
    float4 sv = *(const float4*)&so_g[(b * 128 + n) * 32 + c0];
    float4 gv = *(const float4*)&gst[b * 32 + c0];
    *(float4*)&bufA[row][c0] = sv;
    *(float4*)&bufA[row][32 + c0] = gv;
    *(float4*)&smi[b * 8192 + n * 64 + c0] = sv;
    *(float4*)&smi[b * 8192 + n * 64 + 32 + c0] = gv;
  }
  __syncthreads();
#pragma unroll
  for (int oi = 0; oi < 8; oi++) {
    int o = lane * 8 + oi;
    float a = b_a1[o];
#pragma unroll 8
    for (int k = 0; k < 64; k++) a += w_a1[o * 64 + k] * bufA[row][k];
    bufB[row][o] = fmaxf(a, 0.f);
  }
  __syncthreads();
  float ps = 0.f;
#pragma unroll
  for (int oi = 0; oi < 4; oi++) {
    int o = lane * 4 + oi;
    float a = b_a2[o];
#pragma unroll 8
    for (int k = 0; k < 64; k++) a += w_a2[o * 64 + k] * bufB[row][k];
    ps += w_a3[o] * fmaxf(a, 0.f);
  }
  for (int d = 4; d >= 1; d >>= 1) ps += __shfl_xor(ps, d, 8);
  if (lane == 0) {
    float sc = ps + b_a3[0];
    se_g[b * 128 + n] = (sc != 0.f) ? expf(sc) : 0.f;
  }
}

__global__ __launch_bounds__(128) void k4d_wts(const float* __restrict__ se_g,
                                               float* __restrict__ wts) {
  int b = blockIdx.x, n = threadIdx.x;
  __shared__ float red[128];
  float se = se_g[b * 128 + n];
  red[n] = se;
  __syncthreads();
  for (int s = 64; s >= 1; s >>= 1) {
    if (n < s) red[n] += red[n + s];
    __syncthreads();
  }
  wts[b * 128 + n] = se / red[0];
}

// GRU r-gate
__global__ __launch_bounds__(256) void k5a_r(
    const float* __restrict__ smi, const float* __restrict__ wts,
    const float* __restrict__ w_r, float* __restrict__ rh) {
  int cch = blockIdx.x, b = blockIdx.y, t = threadIdx.x;
  __shared__ float smi_s[128 * 65];
  __shared__ float wts_s[128];
  for (int idx = t; idx < 8192; idx += 256) {
    int n = idx >> 6, k = idx & 63;
    smi_s[n * 65 + k] = smi[b * 8192 + idx];
  }
  if (t < 128) wts_s[t] = wts[b * 128 + t];
  __syncthreads();
  int c = cch * 16 + (t >> 4), l = t & 15;
  float accs[8];
#pragma unroll
  for (int m = 0; m < 8; m++) accs[m] = 0.f;
  const float* wr = &w_r[c * 128];
  for (int k = 0; k < 64; k++) {
    float wv = wr[k];
#pragma unroll
    for (int m = 0; m < 8; m++) accs[m] += wv * smi_s[(l + 16 * m) * 65 + k];
  }
  for (int c2 = 0; c2 < 64; c2++) {
    float wv = wr[64 + c2];
    float g0 = wts_s[2 * c2], g1 = wts_s[2 * c2 + 1];
#pragma unroll
    for (int m = 0; m < 8; m++) {
      int nb = (m >> 2) & 1, nl = l + 16 * (m & 3);
      accs[m] += wv * ((nb ? g1 : g0) * smi_s[(2 * c2 + nb) * 65 + nl]);
    }
  }
#pragma unroll
  for (int m = 0; m < 8; m++) {
    int n = l + 16 * m;
    float r = 1.f / (1.f + expf(-accs[m]));
    rh[(b * 64 + c) * 128 + n] = r * smi_s[n * 65 + c];
  }
}

// GRU z, q, hn, mean over n
__global__ __launch_bounds__(256) void k5b_gru(
    const float* __restrict__ smi, const float* __restrict__ wts,
    const float* __restrict__ rh, const float* __restrict__ w_z,
    const float* __restrict__ w_q, float* __restrict__ hnm) {
  int och = blockIdx.x, b = blockIdx.y, t = threadIdx.x;
  __shared__ float smi_s[128 * 65];
  __shared__ float wts_s[128];
  for (int idx = t; idx < 8192; idx += 256) {
    int n = idx >> 6, k = idx & 63;
    smi_s[n * 65 + k] = smi[b * 8192 + idx];
  }
  if (t < 128) wts_s[t] = wts[b * 128 + t];
  __syncthreads();
  int o = och * 16 + (t >> 4), l = t & 15;
  float az[8], aq[8];
#pragma unroll
  for (int m = 0; m < 8; m++) { az[m] = 0.f; aq[m] = 0.f; }
  const float* wz = &w_z[o * 128];
  const float* wq = &w_q[o * 128];
  const float* rhb = rh + b * 8192;
  for (int k = 0; k < 64; k++) {
    float wv = wz[k];
#pragma unroll
    for (int m = 0; m < 8; m++) az[m] += wv * smi_s[(l + 16 * m) * 65 + k];
  }
  for (int c = 0; c < 64; c++) {
    float wv = wq[c];
#pragma unroll
    for (int m = 0; m < 8; m++) aq[m] += wv * rhb[c * 128 + l + 16 * m];
  }
  for (int c2 = 0; c2 < 64; c2++) {
    float wvz = wz[64 + c2], wvq = wq[64 + c2];
    float g0 = wts_s[2 * c2], g1 = wts_s[2 * c2 + 1];
#pragma unroll
    for (int m = 0; m < 8; m++) {
      int nb = (m >> 2) & 1, nl = l + 16 * (m & 3);
      float gin = (nb ? g1 : g0) * smi_s[(2 * c2 + nb) * 65 + nl];
      az[m] += wvz * gin;
      aq[m] += wvq * gin;
    }
  }
  float part = 0.f;
#pragma unroll
  for (int m = 0; m < 8; m++) {
    int n = l + 16 * m;
    float z = 1.f / (1.f + expf(-az[m]));
    float q = tanhf(aq[m]);
    float h0 = smi_s[n * 65 + o];
    part += (1.f - z) * h0 + z * q;
  }
  for (int d = 8; d >= 1; d >>= 1) part += __shfl_xor(part, d, 16);
  if (l == 0) hnm[b * 64 + o] = part * (1.f / 128.f);
}

__global__ __launch_bounds__(128, 1) void k6_head(
    const float* __restrict__ state, const float* __restrict__ hnm,
    const float* __restrict__ w_m1, const float* __restrict__ b_m1,
    const float* __restrict__ w_m2, const float* __restrict__ b_m2,
    const float* __restrict__ w_m3, const float* __restrict__ b_m3,
    float* __restrict__ out) {
  int b = blockIdx.x, t = threadIdx.x;
  __shared__ float joint[70];
  __shared__ float m1s[128];
  __shared__ float red[64];
  if (t < 6) joint[t] = state[b * 1664 + t];
  if (t < 64) joint[6 + t] = hnm[b * 64 + t];
  __syncthreads();
  float a = b_m1[t];
#pragma unroll 2
  for (int k = 0; k < 70; k++) a += w_m1[t * 70 + k] * joint[k];
  m1s[t] = fmaxf(a, 0.f);
  __syncthreads();
  if (t < 64) {
    float a2 = b_m2[t];
#pragma unroll 8
    for (int k = 0; k < 128; k++) a2 += w_m2[t * 128 + k] * m1s[k];
    red[t] = fmaxf(a2, 0.f) * w_m3[t];
  }
  __syncthreads();
  for (int s = 32; s >= 1; s >>= 1) {
    if (t < s) red[t] += red[t + s];
    __syncthreads();
  }
  if (t == 0) out[b] = red[0] + b_m3[0];
}

extern "C" void kernel_launch(void* const* d_in, const int* in_sizes, int n_in,
                              void* d_out, int out_size, void* d_ws, size_t ws_size,
                              hipStream_t stream) {
  const float* state = (const float*)d_in[0];
  const float* w_in1 = (const float*)d_in[1];
  const float* b_in1 = (const float*)d_in[2];
  const float* w_in2 = (const float*)d_in[3];
  const float* b_in2 = (const float*)d_in[4];
  const float* w_c1  = (const float*)d_in[5];
  const float* b_c1  = (const float*)d_in[6];
  const float* w_c2  = (const float*)d_in[7];
  const float* b_c2  = (const float*)d_in[8];
  const float* w_ia1 = (const float*)d_in[9];
  const float* b_ia1 = (const float*)d_in[10];
  const float* w_ia2 = (const float*)d_in[11];
  const float* b_ia2 = (const float*)d_in[12];
  const float* w_s1  = (const float*)d_in[13];
  const float* b_s1  = (const float*)d_in[14];
  const float* w_s2  = (const float*)d_in[15];
  const float* b_s2  = (const float*)d_in[16];
  const float* w_a1  = (const float*)d_in[17];
  const float* b_a1  = (const float*)d_in[18];
  const float* w_a2  = (const float*)d_in[19];
  const float* b_a2  = (const float*)d_in[20];
  const float* w_a3  = (const float*)d_in[21];
  const float* b_a3  = (const float*)d_in[22];
  const float* w_z   = (const float*)d_in[23];
  const float* w_r   = (const float*)d_in[24];
  const float* w_q   = (const float*)d_in[25];
  const float* w_m1  = (const float*)d_in[26];
  const float* b_m1  = (const float*)d_in[27];
  const float* w_m2  = (const float*)d_in[28];
  const float* b_m2  = (const float*)d_in[29];
  const float* w_m3  = (const float*)d_in[30];
  const float* b_m3  = (const float*)d_in[31];
  float* ws    = (float*)d_ws;
  float* f_    = ws;
  float* R_    = ws + 262144;
  float* C_    = ws + 1835008;
  float* D_    = ws + 3407872;
  float* afa_  = ws + 6029312;
  float* smi_  = ws + 6291456;
  float* wts_  = ws + 6815744;
  float* rh_   = ws + 6823936;
  float* hnm_  = ws + 7348224;
  unsigned short* Apack_ = (unsigned short*)(ws + 7352320);
  float* so_   = ws + 7376896;
  float* gst_  = ws + 7639040;
  float* se_   = ws + 7641088;
  float* out   = (float*)d_out;

  k0_pack<<<1, 256, 0, stream>>>(w_c2, Apack_);
  k1_front<<<dim3(64, 4), 128, 0, stream>>>(state, w_in1, b_in1, w_in2, b_in2, f_);
  k2_pre<<<dim3(16, 64), 128, 0, stream>>>(f_, w_c1, R_, C_, D_);
  k3_conv2<<<dim3(64, 64), 256, 40960, stream>>>(f_, R_, C_, D_, b_c1, Apack_,
                                                 b_c2, afa_);
  k4a_sort<<<256, 256, 0, stream>>>(state, f_, afa_, w_ia1, b_ia1, w_ia2, b_ia2,
                                    w_s1, b_s1, w_s2, b_s2, so_);
  k4b_gstate<<<64, 128, 0, stream>>>(so_, gst_);
  k4c_attn<<<256, 256, 0, stream>>>(so_, gst_, w_a1, b_a1, w_a2, b_a2, w_a3,
                                    b_a3, smi_, se_);
  k4d_wts<<<64, 128, 0, stream>>>(se_, wts_);
  k5a_r<<<dim3(4, 64), 256, 0, stream>>>(smi_, wts_, w_r, rh_);
  k5b_gru<<<dim3(4, 64), 256, 0, stream>>>(smi_, wts_, rh_, w_z, w_q, hnm_);
  k6_head<<<64, 128, 0, stream>>>(state, hnm_, w_m1, b_m1, w_m2, b_m2, w_m3,
                                  b_m3, out);
}

// Round 9
// 591.339 us; speedup vs baseline: 1.0688x; 1.0688x over previous
//
#include <hip/hip_runtime.h>
#include <math.h>

// ValueNetwork forward. conv2 via split-bf16 MFMA (3-pass hi/lo),
// software-pipelined double-buffered quarter-K LDS rebuild.
// ws layout (floats):
//  f    [64][32][128]        @ 0        (262144)
//  R    [64][3][64][128]     @ 262144   (1572864)
//  C    [64][3][64][128]     @ 1835008  (1572864)
//  D    [64][64][128][5]     @ 3407872  (2621440)
//  afa  [64][32][128]        @ 6029312  (262144)
//  smi  [64][128][64]        @ 6291456  (524288)
//  wts  [64][128]            @ 6815744  (8192)
//  rh   [64][64][128]        @ 6823936  (524288)
//  hnm  [64][64]             @ 7348224  (4096)
//  Apack[2][9][4][64][8] u16 @ 7352320  (18432 f32-equiv)
//  so   [64][128][32]        @ 7376896  (262144)
//  gst  [64][32]             @ 7639040  (2048)
//  se   [64][128]            @ 7641088  (8192)

typedef short bf16x4 __attribute__((ext_vector_type(4)));
typedef short bf16x8 __attribute__((ext_vector_type(8)));
typedef float f32x16 __attribute__((ext_vector_type(16)));

__device__ inline unsigned int bf16_rne(float x) {
  unsigned int u = __float_as_uint(x);
  return (u + 0x7fffu + ((u >> 16) & 1u)) >> 16;
}

#define MF(A, B, Cc) __builtin_amdgcn_mfma_f32_32x32x16_bf16((A), (B), (Cc), 0, 0, 0)

// k0: pack w_c2 [o2 32][cin 64][rx 9] fp32 -> Apack[p2][rx9][chunk4][lane64][8] bf16
__global__ __launch_bounds__(256) void k0_pack(const float* __restrict__ w_c2,
                                               unsigned short* __restrict__ Apack) {
  for (int idx = threadIdx.x; idx < 36864; idx += 256) {
    int p = idx / 18432, rem = idx % 18432;
    int rx = rem >> 11, r2 = rem & 2047;
    int chunk = r2 >> 9, r3 = r2 & 511;
    int lane = r3 >> 3, i8 = r3 & 7;
    int o2 = lane & 31, k8 = lane >> 5;
    int cin = chunk * 16 + k8 * 8 + i8;
    float v = w_c2[(o2 * 64 + cin) * 9 + rx];
    unsigned int hi = bf16_rne(v);
    float hif = __uint_as_float(hi << 16);
    unsigned int lo = bf16_rne(v - hif);
    Apack[idx] = (unsigned short)(p ? lo : hi);
  }
}

// front MLP: agents(7) -> 64 relu -> 32 relu, f[b][c][n]
__global__ __launch_bounds__(128) void k1_front(
    const float* __restrict__ state, const float* __restrict__ w_in1,
    const float* __restrict__ b_in1, const float* __restrict__ w_in2,
    const float* __restrict__ b_in2, float* __restrict__ f) {
  int b = blockIdx.x, nq = blockIdx.y, t = threadIdx.x;
  int row = t >> 2, lane = t & 3;
  int n = nq * 32 + row;
  __shared__ float hs[32][66];
  const float* st = state + (b * 128 + n) * 13 + 6;
  float a[7];
#pragma unroll
  for (int k = 0; k < 7; k++) a[k] = st[k];
  for (int oi = 0; oi < 16; oi++) {
    int o = lane * 16 + oi;
    float acc = b_in1[o];
#pragma unroll
    for (int k = 0; k < 7; k++) acc += w_in1[o * 7 + k] * a[k];
    hs[row][o] = fmaxf(acc, 0.f);
  }
  __syncthreads();
  for (int ci = 0; ci < 8; ci++) {
    int c = lane * 8 + ci;
    float acc = b_in2[c];
#pragma unroll 8
    for (int k = 0; k < 64; k++) acc += w_in2[c * 64 + k] * hs[row][k];
    f[(b * 32 + c) * 128 + n] = fmaxf(acc, 0.f);
  }
}

// conv1 low-rank precompute. grid (og=16, b=64), 128 threads = i; 4 o per block.
__global__ __launch_bounds__(128) void k2_pre(
    const float* __restrict__ f, const float* __restrict__ w_c1,
    float* __restrict__ R, float* __restrict__ C, float* __restrict__ D) {
  int og = blockIdx.x, b = blockIdx.y, t = threadIdx.x;
  int o0 = og * 4;
  __shared__ float fL[4096];
  __shared__ float w1s[1152];
  __shared__ float wrow[1152];
  __shared__ float wcol[1152];
  for (int idx = t; idx < 4096; idx += 128) fL[idx] = f[b * 4096 + idx];
  for (int idx = t; idx < 1152; idx += 128) w1s[idx] = w_c1[o0 * 288 + idx];
  __syncthreads();
  if (t < 128) {
    int ol = t >> 5, c = t & 31;
    int base = ol * 288 + c * 9;
#pragma unroll
    for (int di = 0; di < 3; di++) {
      float w0 = w1s[base + di * 3 + 0], w1 = w1s[base + di * 3 + 1],
            w2 = w1s[base + di * 3 + 2];
      wrow[ol * 288 + (c * 3 + di) * 3 + 0] = w1 + w2;
      wrow[ol * 288 + (c * 3 + di) * 3 + 1] = w0 + w1 + w2;
      wrow[ol * 288 + (c * 3 + di) * 3 + 2] = w0 + w1;
    }
#pragma unroll
    for (int dj = 0; dj < 3; dj++) {
      float w0 = w1s[base + 0 * 3 + dj], w1 = w1s[base + 1 * 3 + dj],
            w2 = w1s[base + 2 * 3 + dj];
      wcol[ol * 288 + (c * 3 + dj) * 3 + 0] = w1 + w2;
      wcol[ol * 288 + (c * 3 + dj) * 3 + 1] = w0 + w1 + w2;
      wcol[ol * 288 + (c * 3 + dj) * 3 + 2] = w0 + w1;
    }
  }
  __syncthreads();
  int i = t;
  for (int ol = 0; ol < 4; ol++) {
    int o = o0 + ol;
    float r0 = 0, r1 = 0, r2 = 0, c0 = 0, c1 = 0, c2 = 0;
    float d0 = 0, d1 = 0, d2 = 0, d3 = 0, d4 = 0;
    for (int c = 0; c < 32; c++) {
      float fm = (i >= 1) ? fL[c * 128 + i - 1] : 0.f;
      float f0 = fL[c * 128 + i];
      float fp = (i < 127) ? fL[c * 128 + i + 1] : 0.f;
      const float* wr = &wrow[ol * 288 + c * 9];
      r0 += fm * wr[0] + f0 * wr[3] + fp * wr[6];
      r1 += fm * wr[1] + f0 * wr[4] + fp * wr[7];
      r2 += fm * wr[2] + f0 * wr[5] + fp * wr[8];
      const float* wc = &wcol[ol * 288 + c * 9];
      c0 += fm * wc[0] + f0 * wc[3] + fp * wc[6];
      c1 += fm * wc[1] + f0 * wc[4] + fp * wc[7];
      c2 += fm * wc[2] + f0 * wc[5] + fp * wc[8];
      const float* wp = &w1s[ol * 288 + c * 9];
      d0 += fm * wp[2];
      d1 += fm * wp[1] + f0 * wp[5];
      d2 += fm * wp[0] + f0 * wp[4] + fp * wp[8];
      d3 += f0 * wp[3] + fp * wp[7];
      d4 += fp * wp[6];
    }
    R[((b * 3 + 0) * 64 + o) * 128 + i] = r0;
    R[((b * 3 + 1) * 64 + o) * 128 + i] = r1;
    R[((b * 3 + 2) * 64 + o) * 128 + i] = r2;
    C[((b * 3 + 0) * 64 + o) * 128 + i] = c0;
    C[((b * 3 + 1) * 64 + o) * 128 + i] = c1;
    C[((b * 3 + 2) * 64 + o) * 128 + i] = c2;
    float* dp = &D[((b * 64 + o) * 128 + i) * 5];
    dp[0] = d0; dp[1] = d1; dp[2] = d2; dp[3] = d3; dp[4] = d4;
  }
}

// k3: conv2 via MFMA + softmax + afa. grid (iblk=64, b=64), 256 thr.
// Dynamic LDS 81920 B = 2 buffers of 40960 B: G[prec2][ipl4][j128][stride20 u16].
// Software pipeline per chunk: loadA (oldest vmcnt) -> prefetch next chunk's
// R/C/D into regs (younger, stays in flight) -> MFMA(buf qt&1) -> convert+store
// next chunk into other buffer -> ONE barrier. Epilogue stride 129 (conflicts).
__global__ __launch_bounds__(256, 2) void k3_conv2(
    const float* __restrict__ f, const float* __restrict__ R,
    const float* __restrict__ C, const float* __restrict__ D,
    const float* __restrict__ b_c1, const unsigned short* __restrict__ Apack,
    const float* __restrict__ b_c2, float* __restrict__ afa) {
  extern __shared__ unsigned short G[];  // 40960 u16 = 81920 B
  int iblk = blockIdx.x, b = blockIdx.y, t = threadIdx.x;
  int i0 = iblk * 2;
  int lane = t & 63, jt = t >> 6;
  int nn = lane & 31;
  int kh8 = (lane >> 5) * 8;
  const bf16x8* A8 = (const bf16x8*)Apack;
  bf16x8 zero8 = {0, 0, 0, 0, 0, 0, 0, 0};
  f32x16 acc0 = {0, 0, 0, 0, 0, 0, 0, 0, 0, 0, 0, 0, 0, 0, 0, 0};
  f32x16 acc1 = {0, 0, 0, 0, 0, 0, 0, 0, 0, 0, 0, 0, 0, 0, 0, 0};

  int jlane = t & 31;
  int iplr = (t >> 5) & 3;
  int ch = t >> 7;
  int ipr = i0 - 1 + iplr;
  bool rowok = (ipr >= 0 && ipr <= 127);
  int ipc = ipr < 0 ? 0 : (ipr > 127 ? 127 : ipr);
  int ic = (ipc == 0) ? 0 : ((ipc == 127) ? 2 : 1);
  // D-band hit is fixed per thread (band width 5 < jr spacing 32)
  int hit_jr = -1, hit_rel = 0;
#pragma unroll
  for (int jr = 0; jr < 4; jr++) {
    int rel = jlane + jr * 32 - ipr + 2;
    if (rel >= 0 && rel < 5) { hit_jr = jr; hit_rel = rel; }
  }

  float pC[4][2][4];  // [cp][cin01][jr]
  float pR[4][2];
  float pEv[4][2];    // edge R (row0 if jlane==0, row2 if jlane==31)
  float pD[4][2];

  auto prefetch = [&](int nqt) {
#pragma unroll
    for (int cp = 0; cp < 4; cp++) {
      int cc0 = (ch * 4 + cp) * 2;
      int cin0 = nqt * 16 + cc0;
      const float* Rr = &R[((b * 3 + 1) * 64 + cin0) * 128 + ipc];
      pR[cp][0] = Rr[0];
      pR[cp][1] = Rr[128];
      if (jlane == 0) {
        const float* R0 = &R[((b * 3 + 0) * 64 + cin0) * 128 + ipc];
        pEv[cp][0] = R0[0]; pEv[cp][1] = R0[128];
      } else if (jlane == 31) {
        const float* R2 = &R[((b * 3 + 2) * 64 + cin0) * 128 + ipc];
        pEv[cp][0] = R2[0]; pEv[cp][1] = R2[128];
      }
      const float* C0 = &C[((b * 3 + ic) * 64 + cin0) * 128 + jlane];
#pragma unroll
      for (int jr = 0; jr < 4; jr++) {
        pC[cp][0][jr] = C0[jr * 32];
        pC[cp][1][jr] = C0[128 + jr * 32];
      }
      if (hit_jr >= 0) {
        const float* Dp = &D[((b * 64 + cin0) * 128 + ipc) * 5 + hit_rel];
        pD[cp][0] = Dp[0];
        pD[cp][1] = Dp[640];
      }
    }
  };
  auto store_buf = [&](int nqt, int ub) {
#pragma unroll
    for (int cp = 0; cp < 4; cp++) {
      int cc0 = (ch * 4 + cp) * 2;
      int cin0 = nqt * 16 + cc0;
      float bias0 = b_c1[cin0], bias1 = b_c1[cin0 + 1];
      float base0 = pR[cp][0] + bias0, base1 = pR[cp][1] + bias1;
      float e0 = pEv[cp][0] + bias0, e1 = pEv[cp][1] + bias1;
#pragma unroll
      for (int jr = 0; jr < 4; jr++) {
        int j = jlane + jr * 32;
        float v0 = base0 - pC[cp][0][jr];
        float v1 = base1 - pC[cp][1][jr];
        if (jlane == 0 && jr == 0) { v0 = e0 - pC[cp][0][0]; v1 = e1 - pC[cp][1][0]; }
        if (jlane == 31 && jr == 3) { v0 = e0 - pC[cp][0][3]; v1 = e1 - pC[cp][1][3]; }
        if (hit_jr == jr) { v0 += pD[cp][0]; v1 += pD[cp][1]; }
        v0 = rowok ? fmaxf(v0, 0.f) : 0.f;
        v1 = rowok ? fmaxf(v1, 0.f) : 0.f;
        unsigned int h0 = bf16_rne(v0), h1 = bf16_rne(v1);
        unsigned int l0 = bf16_rne(v0 - __uint_as_float(h0 << 16));
        unsigned int l1 = bf16_rne(v1 - __uint_as_float(h1 << 16));
        unsigned int off = (unsigned)(ub + (iplr * 128 + j) * 20 + cc0);
        *(unsigned int*)&G[off] = h0 | (h1 << 16);
        *(unsigned int*)&G[off + 10240] = l0 | (l1 << 16);
      }
    }
  };

  prefetch(0);
  store_buf(0, 0);
  __syncthreads();

  for (int qt = 0; qt < 4; qt++) {
    int ub = (qt & 1) * 20480;
    // A-fragments FIRST: they become the oldest outstanding vmcnt entries,
    // so the MFMA waits release them without draining the prefetch below.
    bf16x8 Ah[9], Al[9];
#pragma unroll
    for (int rx = 0; rx < 9; rx++) {
      Ah[rx] = A8[(rx * 4 + qt) * 64 + lane];
      Al[rx] = A8[((9 + rx) * 4 + qt) * 64 + lane];
    }
    if (qt < 3) prefetch(qt + 1);  // in flight across the MFMA phase
#pragma unroll
    for (int x = 0; x < 3; x++) {
      int imgj = jt * 32 + nn + x - 1;
      int ij = imgj < 0 ? 0 : (imgj > 127 ? 127 : imgj);
      bool valid = (imgj >= 0 && imgj <= 127);
      bf16x8 bh[4], bl[4];
#pragma unroll
      for (int rr = 0; rr < 4; rr++) {
        int boff = ub + (rr * 128 + ij) * 20 + kh8;
        bf16x4 h0 = *(const bf16x4*)&G[boff];
        bf16x4 h1 = *(const bf16x4*)&G[boff + 4];
        bf16x4 q0 = *(const bf16x4*)&G[boff + 10240];
        bf16x4 q1 = *(const bf16x4*)&G[boff + 10244];
        bf16x8 vh = __builtin_shufflevector(h0, h1, 0, 1, 2, 3, 4, 5, 6, 7);
        bf16x8 vl = __builtin_shufflevector(q0, q1, 0, 1, 2, 3, 4, 5, 6, 7);
        bh[rr] = valid ? vh : zero8;
        bl[rr] = valid ? vl : zero8;
      }
#pragma unroll
      for (int r = 0; r < 3; r++) {
        int rx = r * 3 + x;
        acc0 = MF(Ah[rx], bh[r], acc0);
        acc0 = MF(Ah[rx], bl[r], acc0);
        acc0 = MF(Al[rx], bh[r], acc0);
        acc1 = MF(Ah[rx], bh[r + 1], acc1);
        acc1 = MF(Ah[rx], bl[r + 1], acc1);
        acc1 = MF(Al[rx], bh[r + 1], acc1);
      }
    }
    if (qt < 3) {
      store_buf(qt + 1, ((qt + 1) & 1) * 20480);
      __syncthreads();
    }
  }
  __syncthreads();
  // ---- epilogue: logits -> LDS (stride 129 to break bank conflicts) ----
  float* logits = (float*)G;  // 2*32*129*4 = 33024 B
#pragma unroll
  for (int reg = 0; reg < 16; reg++) {
    int o2 = (reg & 3) + 8 * (reg >> 2) + 4 * (lane >> 5);
    int j = jt * 32 + nn;
    logits[(0 * 32 + o2) * 129 + j] = acc0[reg];
    logits[(1 * 32 + o2) * 129 + j] = acc1[reg];
  }
  __syncthreads();
  // ---- softmax over j + weighted pair reduction (FULLY unrolled: partial
  // unroll demotes vals[]/fj[] to scratch -> 135 MB HBM, rounds 5-7) ----
  {
    int i2 = t >> 7, o2e = (t >> 2) & 31, qd = t & 3;
    const float* lrow = &logits[(i2 * 32 + o2e) * 129 + qd * 32];
    float bias2 = b_c2[o2e];
    float vals[32];
    float mx = -3.0e38f;
#pragma unroll
    for (int s = 0; s < 32; s++) {
      vals[s] = lrow[s] + bias2;
      mx = fmaxf(mx, vals[s]);
    }
    mx = fmaxf(mx, __shfl_xor(mx, 1));
    mx = fmaxf(mx, __shfl_xor(mx, 2));
    float sum = 0.f;
#pragma unroll
    for (int s = 0; s < 32; s++) {
      vals[s] = expf(vals[s] - mx);
      sum += vals[s];
    }
    sum += __shfl_xor(sum, 1);
    sum += __shfl_xor(sum, 2);
    float inv = 1.f / sum;
    int gi = i0 + i2;
    float fi = f[b * 4096 + o2e * 128 + gi];
    float fj[32];
    const float4* frow = (const float4*)&f[b * 4096 + o2e * 128 + qd * 32];
#pragma unroll
    for (int s4 = 0; s4 < 8; s4++) *(float4*)&fj[s4 * 4] = frow[s4];
    float part = 0.f;
#pragma unroll
    for (int s = 0; s < 32; s++) {
      int j = qd * 32 + s;
      float w = vals[s] * inv;
      part += w * (fi - fj[s]);
      if (j == gi) part += w * fi;
    }
    part += __shfl_xor(part, 1);
    part += __shfl_xor(part, 2);
    if (qd == 0) afa[(b * 32 + o2e) * 128 + gi] = part;
  }
}

// k4a: per (b,n): x -> h1 -> ia||self -> s1 -> so. grid 256 blocks, 256 thr.
__global__ __launch_bounds__(256) void k4a_sort(
    const float* __restrict__ state, const float* __restrict__ f,
    const float* __restrict__ afa, const float* __restrict__ w_ia1,
    const float* __restrict__ b_ia1, const float* __restrict__ w_ia2,
    const float* __restrict__ b_ia2, const float* __restrict__ w_s1,
    const float* __restrict__ b_s1, const float* __restrict__ w_s2,
    const float* __restrict__ b_s2, float* __restrict__ so_g) {
  int blk = blockIdx.x;
  int b = blk >> 2, nq = blk & 3;
  int t = threadIdx.x, row = t >> 3, lane = t & 7;
  int n = nq * 32 + row;
  __shared__ float bufA[32][40];
  __shared__ float bufB[32][72];
  {
    int c0 = lane * 4;
    float4 av = *(const float4*)&afa[b * 4096 + n * 32 + c0];
    bufA[row][c0 + 0] = f[b * 4096 + (c0 + 0) * 128 + n] + av.x;
    bufA[row][c0 + 1] = f[b * 4096 + (c0 + 1) * 128 + n] + av.y;
    bufA[row][c0 + 2] = f[b * 4096 + (c0 + 2) * 128 + n] + av.z;
    bufA[row][c0 + 3] = f[b * 4096 + (c0 + 3) * 128 + n] + av.w;
  }
  __syncthreads();
#pragma unroll
  for (int oi = 0; oi < 8; oi++) {
    int o = lane * 8 + oi;
    float a = b_ia1[o];
#pragma unroll 8
    for (int c = 0; c < 32; c++) a += w_ia1[o * 32 + c] * bufA[row][c];
    bufB[row][o] = fmaxf(a, 0.f);
  }
  __syncthreads();
  {
    float r0[4];
#pragma unroll
    for (int oi = 0; oi < 4; oi++) {
      int o = lane * 4 + oi;
      float a = b_ia2[o];
#pragma unroll 8
      for (int k = 0; k < 64; k++) a += w_ia2[o * 64 + k] * bufB[row][k];
      r0[oi] = a;
    }
    __syncthreads();
#pragma unroll
    for (int oi = 0; oi < 4; oi++) bufA[row][lane * 4 + oi] = r0[oi];
    if (lane == 0) {
#pragma unroll
      for (int k = 0; k < 6; k++)
        bufA[row][32 + k] = state[(b * 128 + n) * 13 + k];
    }
  }
  __syncthreads();
#pragma unroll
  for (int oi = 0; oi < 8; oi++) {
    int o = lane * 8 + oi;
    float a = b_s1[o];
#pragma unroll 2
    for (int k = 0; k < 38; k++) a += w_s1[o * 38 + k] * bufA[row][k];
    bufB[row][o] = fmaxf(a, 0.f);
  }
  __syncthreads();
#pragma unroll
  for (int oi = 0; oi < 4; oi++) {
    int o = lane * 4 + oi;
    float a = b_s2[o];
#pragma unroll 8
    for (int k = 0; k < 64; k++) a += w_s2[o * 64 + k] * bufB[row][k];
    so_g[(b * 128 + n) * 32 + o] = a;
  }
}

__global__ __launch_bounds__(128) void k4b_gstate(const float* __restrict__ so_g,
                                                  float* __restrict__ gst) {
  int b = blockIdx.x, t = threadIdx.x;
  int c = t & 31, part = t >> 5;
  __shared__ float red[4][32];
  float a = 0.f;
  for (int nn = 0; nn < 32; nn++) a += so_g[(b * 128 + part * 32 + nn) * 32 + c];
  red[part][c] = a;
  __syncthreads();
  if (t < 32) gst[b * 32 + t] =
      (red[0][t] + red[1][t] + red[2][t] + red[3][t]) * (1.f / 128.f);
}

__global__ __launch_bounds__(256) void k4c_attn(
    const float* __restrict__ so_g, const float* __restrict__ gst,
    const float* __restrict__ w_a1, const float* __restrict__ b_a1,
    const float* __restrict__ w_a2, const float* __restrict__ b_a2,
    const float* __restrict__ w_a3, const float* __restrict__ b_a3,
    float* __restrict__ smi, float* __restrict__ se_g) {
  int blk = blockIdx.x;
  int b = blk >> 2, nq = blk & 3;
  int t = threadIdx.x, row = t >> 3, lane = t & 7;
  int n = nq * 32 + row;
  __shared__ float bufA[32][72];
  __shared__ float bufB[32][72];
  {
    int c0 = lane * 4;
    float4 sv = *(const float4*)&so_g[(b * 128 + n) * 32 + c0];
    float4 gv = *(const float4*)&gst[b * 32 + c0];
    *(float4*)&bufA[row][c0] = sv;
    *(float4*)&bufA[row][32 + c0] = gv;
    *(float4*)&smi[b * 8192 + n * 64 + c0] = sv;
    *(float4*)&smi[b * 8192 + n * 64 + 32 + c0] = gv;
  }
  __syncthreads();
#pragma unroll
  for (int oi = 0; oi < 8; oi++) {
    int o = lane * 8 + oi;
    float a = b_a1[o];
#pragma unroll 8
    for (int k = 0; k < 64; k++) a += w_a1[o * 64 + k] * bufA[row][k];
    bufB[row][o] = fmaxf(a, 0.f);
  }
  __syncthreads();
  float ps = 0.f;
#pragma unroll
  for (int oi = 0; oi < 4; oi++) {
    int o = lane * 4 + oi;
    float a = b_a2[o];
#pragma unroll 8
    for (int k = 0; k < 64; k++) a += w_a2[o * 64 + k] * bufB[row][k];
    ps += w_a3[o] * fmaxf(a, 0.f);
  }
  for (int d = 4; d >= 1; d >>= 1) ps += __shfl_xor(ps, d, 8);
  if (lane == 0) {
    float sc = ps + b_a3[0];
    se_g[b * 128 + n] = (sc != 0.f) ? expf(sc) : 0.f;
  }
}

__global__ __launch_bounds__(128) void k4d_wts(const float* __restrict__ se_g,
                                               float* __restrict__ wts) {
  int b = blockIdx.x, n = threadIdx.x;
  __shared__ float red[128];
  float se = se_g[b * 128 + n];
  red[n] = se;
  __syncthreads();
  for (int s = 64; s >= 1; s >>= 1) {
    if (n < s) red[n] += red[n + s];
    __syncthreads();
  }
  wts[b * 128 + n] = se / red[0];
}

// GRU r-gate
__global__ __launch_bounds__(256) void k5a_r(
    const float* __restrict__ smi, const float* __restrict__ wts,
    const float* __restrict__ w_r, float* __restrict__ rh) {
  int cch = blockIdx.x, b = blockIdx.y, t = threadIdx.x;
  __shared__ float smi_s[128 * 65];
  __shared__ float wts_s[128];
  for (int idx = t; idx < 8192; idx += 256) {
    int n = idx >> 6, k = idx & 63;
    smi_s[n * 65 + k] = smi[b * 8192 + idx];
  }
  if (t < 128) wts_s[t] = wts[b * 128 + t];
  __syncthreads();
  int c = cch * 16 + (t >> 4), l = t & 15;
  float accs[8];
#pragma unroll
  for (int m = 0; m < 8; m++) accs[m] = 0.f;
  const float* wr = &w_r[c * 128];
  for (int k = 0; k < 64; k++) {
    float wv = wr[k];
#pragma unroll
    for (int m = 0; m < 8; m++) accs[m] += wv * smi_s[(l + 16 * m) * 65 + k];
  }
  for (int c2 = 0; c2 < 64; c2++) {
    float wv = wr[64 + c2];
    float g0 = wts_s[2 * c2], g1 = wts_s[2 * c2 + 1];
#pragma unroll
    for (int m = 0; m < 8; m++) {
      int nb = (m >> 2) & 1, nl = l + 16 * (m & 3);
      accs[m] += wv * ((nb ? g1 : g0) * smi_s[(2 * c2 + nb) * 65 + nl]);
    }
  }
#pragma unroll
  for (int m = 0; m < 8; m++) {
    int n = l + 16 * m;
    float r = 1.f / (1.f + expf(-accs[m]));
    rh[(b * 64 + c) * 128 + n] = r * smi_s[n * 65 + c];
  }
}

// GRU z, q, hn, mean over n
__global__ __launch_bounds__(256) void k5b_gru(
    const float* __restrict__ smi, const float* __restrict__ wts,
    const float* __restrict__ rh, const float* __restrict__ w_z,
    const float* __restrict__ w_q, float* __restrict__ hnm) {
  int och = blockIdx.x, b = blockIdx.y, t = threadIdx.x;
  __shared__ float smi_s[128 * 65];
  __shared__ float wts_s[128];
  for (int idx = t; idx < 8192; idx += 256) {
    int n = idx >> 6, k = idx & 63;
    smi_s[n * 65 + k] = smi[b * 8192 + idx];
  }
  if (t < 128) wts_s[t] = wts[b * 128 + t];
  __syncthreads();
  int o = och * 16 + (t >> 4), l = t & 15;
  float az[8], aq[8];
#pragma unroll
  for (int m = 0; m < 8; m++) { az[m] = 0.f; aq[m] = 0.f; }
  const float* wz = &w_z[o * 128];
  const float* wq = &w_q[o * 128];
  const float* rhb = rh + b * 8192;
  for (int k = 0; k < 64; k++) {
    float wv = wz[k];
#pragma unroll
    for (int m = 0; m < 8; m++) az[m] += wv * smi_s[(l + 16 * m) * 65 + k];
  }
  for (int c = 0; c < 64; c++) {
    float wv = wq[c];
#pragma unroll
    for (int m = 0; m < 8; m++) aq[m] += wv * rhb[c * 128 + l + 16 * m];
  }
  for (int c2 = 0; c2 < 64; c2++) {
    float wvz = wz[64 + c2], wvq = wq[64 + c2];
    float g0 = wts_s[2 * c2], g1 = wts_s[2 * c2 + 1];
#pragma unroll
    for (int m = 0; m < 8; m++) {
      int nb = (m >> 2) & 1, nl = l + 16 * (m & 3);
      float gin = (nb ? g1 : g0) * smi_s[(2 * c2 + nb) * 65 + nl];
      az[m] += wvz * gin;
      aq[m] += wvq * gin;
    }
  }
  float part = 0.f;
#pragma unroll
  for (int m = 0; m < 8; m++) {
    int n = l + 16 * m;
    float z = 1.f / (1.f + expf(-az[m]));
    float q = tanhf(aq[m]);
    float h0 = smi_s[n * 65 + o];
    part += (1.f - z) * h0 + z * q;
  }
  for (int d = 8; d >= 1; d >>= 1) part += __shfl_xor(part, d, 16);
  if (l == 0) hnm[b * 64 + o] = part * (1.f / 128.f);
}

__global__ __launch_bounds__(128, 1) void k6_head(
    const float* __restrict__ state, const float* __restrict__ hnm,
    const float* __restrict__ w_m1, const float* __restrict__ b_m1,
    const float* __restrict__ w_m2, const float* __restrict__ b_m2,
    const float* __restrict__ w_m3, const float* __restrict__ b_m3,
    float* __restrict__ out) {
  int b = blockIdx.x, t = threadIdx.x;
  __shared__ float joint[70];
  __shared__ float m1s[128];
  __shared__ float red[64];
  if (t < 6) joint[t] = state[b * 1664 + t];
  if (t < 64) joint[6 + t] = hnm[b * 64 + t];
  __syncthreads();
  float a = b_m1[t];
#pragma unroll 2
  for (int k = 0; k < 70; k++) a += w_m1[t * 70 + k] * joint[k];
  m1s[t] = fmaxf(a, 0.f);
  __syncthreads();
  if (t < 64) {
    float a2 = b_m2[t];
#pragma unroll 8
    for (int k = 0; k < 128; k++) a2 += w_m2[t * 128 + k] * m1s[k];
    red[t] = fmaxf(a2, 0.f) * w_m3[t];
  }
  __syncthreads();
  for (int s = 32; s >= 1; s >>= 1) {
    if (t < s) red[t] += red[t + s];
    __syncthreads();
  }
  if (t == 0) out[b] = red[0] + b_m3[0];
}

extern "C" void kernel_launch(void* const* d_in, const int* in_sizes, int n_in,
                              void* d_out, int out_size, void* d_ws, size_t ws_size,
                              hipStream_t stream) {
  const float* state = (const float*)d_in[0];
  const float* w_in1 = (const float*)d_in[1];
  const float* b_in1 = (const float*)d_in[2];
  const float* w_in2 = (const float*)d_in[3];
  const float* b_in2 = (const float*)d_in[4];
  const float* w_c1  = (const float*)d_in[5];
  const float* b_c1  = (const float*)d_in[6];
  const float* w_c2  = (const float*)d_in[7];
  const float* b_c2  = (const float*)d_in[8];
  const float* w_ia1 = (const float*)d_in[9];
  const float* b_ia1 = (const float*)d_in[10];
  const float* w_ia2 = (const float*)d_in[11];
  const float* b_ia2 = (const float*)d_in[12];
  const float* w_s1  = (const float*)d_in[13];
  const float* b_s1  = (const float*)d_in[14];
  const float* w_s2  = (const float*)d_in[15];
  const float* b_s2  = (const float*)d_in[16];
  const float* w_a1  = (const float*)d_in[17];
  const float* b_a1  = (const float*)d_in[18];
  const float* w_a2  = (const float*)d_in[19];
  const float* b_a2  = (const float*)d_in[20];
  const float* w_a3  = (const float*)d_in[21];
  const float* b_a3  = (const float*)d_in[22];
  const float* w_z   = (const float*)d_in[23];
  const float* w_r   = (const float*)d_in[24];
  const float* w_q   = (const float*)d_in[25];
  const float* w_m1  = (const float*)d_in[26];
  const float* b_m1  = (const float*)d_in[27];
  const float* w_m2  = (const float*)d_in[28];
  const float* b_m2  = (const float*)d_in[29];
  const float* w_m3  = (const float*)d_in[30];
  const float* b_m3  = (const float*)d_in[31];
  float* ws    = (float*)d_ws;
  float* f_    = ws;
  float* R_    = ws + 262144;
  float* C_    = ws + 1835008;
  float* D_    = ws + 3407872;
  float* afa_  = ws + 6029312;
  float* smi_  = ws + 6291456;
  float* wts_  = ws + 6815744;
  float* rh_   = ws + 6823936;
  float* hnm_  = ws + 7348224;
  unsigned short* Apack_ = (unsigned short*)(ws + 7352320);
  float* so_   = ws + 7376896;
  float* gst_  = ws + 7639040;
  float* se_   = ws + 7641088;
  float* out   = (float*)d_out;

  k0_pack<<<1, 256, 0, stream>>>(w_c2, Apack_);
  k1_front<<<dim3(64, 4), 128, 0, stream>>>(state, w_in1, b_in1, w_in2, b_in2, f_);
  k2_pre<<<dim3(16, 64), 128, 0, stream>>>(f_, w_c1, R_, C_, D_);
  k3_conv2<<<dim3(64, 64), 256, 81920, stream>>>(f_, R_, C_, D_, b_c1, Apack_,
                                                 b_c2, afa_);
  k4a_sort<<<256, 256, 0, stream>>>(state, f_, afa_, w_ia1, b_ia1, w_ia2, b_ia2,
                                    w_s1, b_s1, w_s2, b_s2, so_);
  k4b_gstate<<<64, 128, 0, stream>>>(so_, gst_);
  k4c_attn<<<256, 256, 0, stream>>>(so_, gst_, w_a1, b_a1, w_a2, b_a2, w_a3,
                                    b_a3, smi_, se_);
  k4d_wts<<<64, 128, 0, stream>>>(se_, wts_);
  k5a_r<<<dim3(4, 64), 256, 0, stream>>>(smi_, wts_, w_r, rh_);
  k5b_gru<<<dim3(4, 64), 256, 0, stream>>>(smi_, wts_, rh_, w_z, w_q, hnm_);
  k6_head<<<64, 128, 0, stream>>>(state, hnm_, w_m1, b_m1, w_m2, b_m2, w_m3,
                                  b_m3, out);
}